// Round 1
// baseline (714.394 us; speedup 1.0000x reference)
//
#include <hip/hip_runtime.h>

#define NN 32768
#define MM 32
#define DD 128
#define OO 64

typedef __bf16 bf16t;
typedef bf16t v8bf __attribute__((ext_vector_type(8)));
typedef float v4f __attribute__((ext_vector_type(4)));
typedef unsigned short u16x8 __attribute__((ext_vector_type(8)));

#define WAVES_PER_BLOCK 4
#define BLOCKS 512
#define TOTAL_WAVES (BLOCKS * WAVES_PER_BLOCK)  // 2048; 32768/2048 = 16 iters, uniform

__global__ __launch_bounds__(256, 2) void hyperedge_kernel(
    const float* __restrict__ X,     // [N, M, D]
    const float* __restrict__ W,     // [D, O]
    const float* __restrict__ bias,  // [O]
    const float* __restrict__ aw,    // [O]
    float* __restrict__ out,         // [N, D]
    float* __restrict__ alph)        // [N, M]
{
    // W fragments: [ks][ct][lane], hi/lo split. 16 KiB each.
    __shared__ u16x8 wfh[4][4][64];
    __shared__ u16x8 wfl[4][4][64];
    // phase-2 partial rows, padded to 132 floats to break bank aliasing. 33 KiB.
    __shared__ __align__(16) float part[WAVES_PER_BLOCK][16][132];
    // per-wave alpha staging
    __shared__ float alds[WAVES_PER_BLOCK][32];

    const int tid  = threadIdx.x;
    const int wave = tid >> 6;
    const int lane = tid & 63;
    const int q    = lane >> 4;   // quad 0..3
    const int lw   = lane & 15;   // low 4 bits

    // ---- Build W hi/lo B-fragments once per block.
    // B-frag (K x N = 32 x 16): lane holds B[k = quad*8 + j][o = lane&15]
    for (int idx = tid; idx < 4 * 4 * 64; idx += 256) {
        int l  = idx & 63;
        int ct = (idx >> 6) & 3;
        int ks = idx >> 8;
        int qq = l >> 4, ll = l & 15;
        int o  = ct * 16 + ll;
        int kb = ks * 32 + qq * 8;
        u16x8 h, lo;
#pragma unroll
        for (int j = 0; j < 8; ++j) {
            float w = W[(kb + j) * OO + o];
            unsigned b = __float_as_uint(w);
            float hf = __uint_as_float(b & 0xffff0000u);
            float lf = w - hf;
            h[j]  = (unsigned short)(b >> 16);
            lo[j] = (unsigned short)(__float_as_uint(lf) >> 16);
        }
        wfh[ks][ct][l] = h;
        wfl[ks][ct][l] = lo;
    }
    __syncthreads();

    float bv[4], av[4];
#pragma unroll
    for (int ct = 0; ct < 4; ++ct) {
        bv[ct] = bias[ct * 16 + lw];
        av[ct] = aw[ct * 16 + lw];
    }

    const int wgid = blockIdx.x * WAVES_PER_BLOCK + wave;

    for (int n = wgid; n < NN; n += TOTAL_WAVES) {
        // ---- Load X[n] into registers (A-fragment friendly + coalesced-per-row)
        // lane holds X[n][m = rt*16 + lw][d = ks*32 + q*8 + j]
        float xr[2][4][8];
        const float* xn = X + (size_t)n * (MM * DD);
#pragma unroll
        for (int rt = 0; rt < 2; ++rt) {
            int m = rt * 16 + lw;
#pragma unroll
            for (int ks = 0; ks < 4; ++ks) {
                const float4 a = *reinterpret_cast<const float4*>(xn + m * DD + ks * 32 + q * 8);
                const float4 b = *reinterpret_cast<const float4*>(xn + m * DD + ks * 32 + q * 8 + 4);
                xr[rt][ks][0] = a.x; xr[rt][ks][1] = a.y; xr[rt][ks][2] = a.z; xr[rt][ks][3] = a.w;
                xr[rt][ks][4] = b.x; xr[rt][ks][5] = b.y; xr[rt][ks][6] = b.z; xr[rt][ks][7] = b.w;
            }
        }

        // ---- z = X @ W via split-bf16 MFMA (3 products: hh + hl + lh)
        v4f acc[2][4];
#pragma unroll
        for (int rt = 0; rt < 2; ++rt)
#pragma unroll
            for (int ct = 0; ct < 4; ++ct)
                acc[rt][ct] = (v4f){0.f, 0.f, 0.f, 0.f};

#pragma unroll
        for (int ks = 0; ks < 4; ++ks) {
            v8bf ah[2], al[2];
#pragma unroll
            for (int rt = 0; rt < 2; ++rt) {
                u16x8 hu, lu;
#pragma unroll
                for (int j = 0; j < 8; ++j) {
                    float x = xr[rt][ks][j];
                    unsigned b = __float_as_uint(x);
                    float hf = __uint_as_float(b & 0xffff0000u);
                    float lf = x - hf;
                    hu[j] = (unsigned short)(b >> 16);
                    lu[j] = (unsigned short)(__float_as_uint(lf) >> 16);
                }
                ah[rt] = __builtin_bit_cast(v8bf, hu);
                al[rt] = __builtin_bit_cast(v8bf, lu);
            }
#pragma unroll
            for (int ct = 0; ct < 4; ++ct) {
                v8bf bh = __builtin_bit_cast(v8bf, wfh[ks][ct][lane]);
                v8bf bl = __builtin_bit_cast(v8bf, wfl[ks][ct][lane]);
#pragma unroll
                for (int rt = 0; rt < 2; ++rt) {
                    acc[rt][ct] = __builtin_amdgcn_mfma_f32_16x16x32_bf16(ah[rt], bh, acc[rt][ct], 0, 0, 0);
                    acc[rt][ct] = __builtin_amdgcn_mfma_f32_16x16x32_bf16(ah[rt], bl, acc[rt][ct], 0, 0, 0);
                    acc[rt][ct] = __builtin_amdgcn_mfma_f32_16x16x32_bf16(al[rt], bh, acc[rt][ct], 0, 0, 0);
                }
            }
        }

        // ---- tanh + logits partials. C/D layout: row = rt*16 + q*4 + r, col o = ct*16 + lw
        float lp[2][4];
#pragma unroll
        for (int rt = 0; rt < 2; ++rt)
#pragma unroll
            for (int r = 0; r < 4; ++r) {
                float s = 0.f;
#pragma unroll
                for (int ct = 0; ct < 4; ++ct) {
                    float z = acc[rt][ct][r] + bv[ct];
                    float e = __expf(2.f * z);
                    float th = 1.f - 2.f / (e + 1.f);
                    s += th * av[ct];
                }
                lp[rt][r] = s;
            }
        // reduce over the 16 column-lanes (low 4 lane bits)
#pragma unroll
        for (int off = 1; off < 16; off <<= 1) {
#pragma unroll
            for (int rt = 0; rt < 2; ++rt)
#pragma unroll
                for (int r = 0; r < 4; ++r)
                    lp[rt][r] += __shfl_xor(lp[rt][r], off, 64);
        }

        // ---- softmax over 32 rows (each quad holds 8 rows; butterfly across quads)
        float mx = -1e30f;
#pragma unroll
        for (int rt = 0; rt < 2; ++rt)
#pragma unroll
            for (int r = 0; r < 4; ++r) mx = fmaxf(mx, lp[rt][r]);
        mx = fmaxf(mx, __shfl_xor(mx, 16, 64));
        mx = fmaxf(mx, __shfl_xor(mx, 32, 64));

        float ex[2][4];
        float ssum = 0.f;
#pragma unroll
        for (int rt = 0; rt < 2; ++rt)
#pragma unroll
            for (int r = 0; r < 4; ++r) {
                ex[rt][r] = __expf(lp[rt][r] - mx);
                ssum += ex[rt][r];
            }
        ssum += __shfl_xor(ssum, 16, 64);
        ssum += __shfl_xor(ssum, 32, 64);
        float inv = 1.f / ssum;

        // stage alphas so each lane can fetch alpha for its X rows (m = rt*16 + lw)
        if (lw == 0) {
#pragma unroll
            for (int rt = 0; rt < 2; ++rt)
#pragma unroll
                for (int r = 0; r < 4; ++r)
                    alds[wave][rt * 16 + q * 4 + r] = ex[rt][r] * inv;
        }
        __syncthreads();
        float ax0 = alds[wave][lw];
        float ax1 = alds[wave][16 + lw];

        // ---- phase 2: out[d] = sum_m alpha[m] * X[m][d]
        // each lane writes alpha-weighted sum of its 2 rows into part[lw][d]
#pragma unroll
        for (int ks = 0; ks < 4; ++ks) {
            float pf[8];
#pragma unroll
            for (int j = 0; j < 8; ++j)
                pf[j] = ax0 * xr[0][ks][j] + ax1 * xr[1][ks][j];
            float4 p0 = {pf[0], pf[1], pf[2], pf[3]};
            float4 p1 = {pf[4], pf[5], pf[6], pf[7]};
            *reinterpret_cast<float4*>(&part[wave][lw][ks * 32 + q * 8]) = p0;
            *reinterpret_cast<float4*>(&part[wave][lw][ks * 32 + q * 8 + 4]) = p1;
        }
        __syncthreads();

        // reduce the 16 partial rows; lanes 0..31 take rows 0..7, lanes 32..63 rows 8..15
        int l5 = lane & 31;
        int ih = lane >> 5;
        float4 s4 = {0.f, 0.f, 0.f, 0.f};
#pragma unroll
        for (int i = 0; i < 8; ++i) {
            const float4 v = *reinterpret_cast<const float4*>(&part[wave][ih * 8 + i][l5 * 4]);
            s4.x += v.x; s4.y += v.y; s4.z += v.z; s4.w += v.w;
        }
        s4.x += __shfl_xor(s4.x, 32, 64);
        s4.y += __shfl_xor(s4.y, 32, 64);
        s4.z += __shfl_xor(s4.z, 32, 64);
        s4.w += __shfl_xor(s4.w, 32, 64);

        if (lane < 32) {
            *reinterpret_cast<float4*>(out + (size_t)n * DD + l5 * 4) = s4;
            // lanes 0..15: ax0 = alpha[lane]; lanes 16..31: ax1 = alpha[lane]
            alph[(size_t)n * MM + lane] = (lane < 16) ? ax0 : ax1;
        }
    }
}

extern "C" void kernel_launch(void* const* d_in, const int* in_sizes, int n_in,
                              void* d_out, int out_size, void* d_ws, size_t ws_size,
                              hipStream_t stream) {
    const float* X    = (const float*)d_in[0];
    const float* W    = (const float*)d_in[1];
    const float* bias = (const float*)d_in[2];
    const float* aw   = (const float*)d_in[3];
    float* out  = (float*)d_out;
    float* alph = out + (size_t)NN * DD;
    hipLaunchKernelGGL(hyperedge_kernel, dim3(BLOCKS), dim3(256), 0, stream,
                       X, W, bias, aw, out, alph);
}